// Round 14
// baseline (148.912 us; speedup 1.0000x reference)
//
#include <hip/hip_runtime.h>
#include <hip/hip_bf16.h>
#include <cstdint>
#include <cstddef>

// MoE FFN: x[2,2048,1024] fp32, 8 experts top-2 + 1 shared expert.
// R1: no-atomic routing.  R2: shared expert fused as expert #8.
// R3: LDS swizzle (conflicts 0).  R9: XCD swizzle (FETCH -> compulsory).
// R12: 2-phase 32-MFMA clusters + fused route/cvt (256² 1-block/CU plateau ~560TF).
// R13 (failed): 128² 2-blocks/CU, but single-barrier phase had an LDS WAR race
//      (STG issued in same segment as other waves' queued reads of that buffer).
// R14: race fixed — phase = LGKM0 -> MFMA -> BARR -> STG -> VMCNT(8) -> RD.
//      All waves' reads of a buffer are DRAINED (lgkmcnt=0) before the barrier
//      that precedes its overwrite. Still 1 barrier/phase, 2 blocks/CU.

#define NTOK 4096
#define DM 1024
#define DH 1024
#define NE 8
#define MAXSLOT_E 9216            // 8192 assignments + 8*128 padding (worst case)
#define MAXSLOT_ALL (MAXSLOT_E + NTOK)  // + shared segment (4096) = 13312
#define NASSIGN (NTOK * 2)
#define NRT (MAXSLOT_ALL / 128)   // 104 row tiles
#define GRID_G (NRT * 8)          // 832 blocks (8 col tiles), 832 % 8 == 0

typedef __attribute__((ext_vector_type(8))) short short8;
typedef __attribute__((ext_vector_type(8))) unsigned short ushort8v;
typedef __attribute__((ext_vector_type(4))) float f32x4;

__device__ __forceinline__ unsigned short f2bf(float f) {
  uint32_t u = __float_as_uint(f);
  return (unsigned short)((u + 0x7FFFu + ((u >> 16) & 1u)) >> 16);  // RNE
}
__device__ __forceinline__ float bf2f(unsigned short h) {
  return __uint_as_float(((uint32_t)h) << 16);
}

__device__ __forceinline__ void async_ld16(const void* g, void* l) {
  __builtin_amdgcn_global_load_lds(
      (const __attribute__((address_space(1))) void*)g,
      (__attribute__((address_space(3))) void*)l, 16, 0, 0);
}

__device__ __forceinline__ void BARR() {
  asm volatile("" ::: "memory");
  __builtin_amdgcn_s_barrier();
  asm volatile("" ::: "memory");
}
__device__ __forceinline__ void LGKM0() {
  asm volatile("s_waitcnt lgkmcnt(0)" ::: "memory");
  __builtin_amdgcn_sched_barrier(0);
}
#define VMCNT(n) asm volatile("s_waitcnt vmcnt(" #n ")" ::: "memory")

// ---- ONE dispatch: 18 weight-matrix transposes (blocks 0..4607) + fused
//      x-convert/route (blocks 4608..5631). Independent work, runs concurrently.
__global__ __launch_bounds__(256) void k_prep(const float* __restrict__ up_w,
                                              const float* __restrict__ down_w,
                                              const float* __restrict__ sh_up,
                                              const float* __restrict__ sh_dn,
                                              unsigned short* __restrict__ upT,
                                              unsigned short* __restrict__ dnT,
                                              unsigned short* __restrict__ shuT,
                                              unsigned short* __restrict__ shdT,
                                              const float* __restrict__ x,
                                              const float* __restrict__ gw,
                                              unsigned short* __restrict__ xb,
                                              int* __restrict__ tok_e,
                                              float* __restrict__ tok_w) {
  __shared__ float tile[64][65];
  int id = blockIdx.x;
  if (id < 4608) {
    int z = id >> 8, rem = id & 255;
    int r0 = (rem >> 4) * 64, c0 = (rem & 15) * 64;
    const float* S;
    unsigned short* D;
    if (z < 8)        { S = up_w   + (size_t)z * (DM * DH);       D = upT + (size_t)z * (DM * DH); }
    else if (z < 16)  { S = down_w + (size_t)(z - 8) * (DM * DH); D = dnT + (size_t)(z - 8) * (DM * DH); }
    else if (z == 16) { S = sh_up;  D = shuT; }
    else              { S = sh_dn;  D = shdT; }
    int t = threadIdx.x;
    int fc = (t & 15) * 4, rr = t >> 4;
#pragma unroll
    for (int i = 0; i < 4; ++i) {
      int r = rr + i * 16;
      float4 v = *(const float4*)&S[(size_t)(r0 + r) * 1024 + c0 + fc];
      tile[r][fc + 0] = v.x; tile[r][fc + 1] = v.y;
      tile[r][fc + 2] = v.z; tile[r][fc + 3] = v.w;
    }
    __syncthreads();
    int c = t >> 2;
    int rs = (t & 3) * 16;
#pragma unroll
    for (int j = 0; j < 2; ++j) {
      int rb = rs + j * 8;
      ushort8v o;
#pragma unroll
      for (int k = 0; k < 8; ++k) o[k] = f2bf(tile[rb + k][c]);
      *(ushort8v*)&D[(size_t)(c0 + c) * 1024 + r0 + rb] = o;
    }
  } else {
    int wave = threadIdx.x >> 6, lane = threadIdx.x & 63;
    int t = (id - 4608) * 4 + wave;
    const float4* xt = (const float4*)(x + (size_t)t * DM);
    unsigned short* xbt = xb + (size_t)t * DM;
    float acc[NE];
#pragma unroll
    for (int e = 0; e < NE; ++e) acc[e] = 0.f;
#pragma unroll
    for (int c = 0; c < 4; ++c) {
      int idx = lane + c * 64;
      float4 v = xt[idx];
      ushort4 o;
      o.x = f2bf(v.x); o.y = f2bf(v.y); o.z = f2bf(v.z); o.w = f2bf(v.w);
      *(ushort4*)(xbt + idx * 4) = o;
#pragma unroll
      for (int e = 0; e < NE; ++e) {
        float4 g = ((const float4*)(gw + (size_t)e * DM))[idx];
        acc[e] += v.x * g.x + v.y * g.y + v.z * g.z + v.w * g.w;
      }
    }
#pragma unroll
    for (int e = 0; e < NE; ++e) {
#pragma unroll
      for (int off = 32; off; off >>= 1) acc[e] += __shfl_xor(acc[e], off, 64);
    }
    if (lane == 0) {
      float m = acc[0];
#pragma unroll
      for (int e = 1; e < NE; ++e) m = fmaxf(m, acc[e]);
      float p[NE], s = 0.f;
#pragma unroll
      for (int e = 0; e < NE; ++e) { p[e] = __expf(acc[e] - m); s += p[e]; }
#pragma unroll
      for (int e = 0; e < NE; ++e) p[e] /= s;
      int i0 = 0;
#pragma unroll
      for (int e = 1; e < NE; ++e) if (p[e] > p[i0]) i0 = e;
      int i1 = (i0 == 0) ? 1 : 0;
#pragma unroll
      for (int e = 0; e < NE; ++e) if (e != i0 && p[e] > p[i1]) i1 = e;
      float w0 = p[i0], w1 = p[i1];
      float dnm = w0 + w1 + 1e-20f;
      w0 /= dnm; w1 /= dnm;
      tok_e[t * 2 + 0] = i0; tok_e[t * 2 + 1] = i1;
      tok_w[t * 2 + 0] = w0; tok_w[t * 2 + 1] = w1;
    }
  }
}

// --------- slot assignment: single block, ballot-based stable counting sort ---------
// experts padded to 128 rows (GEMM tile = 128)
__global__ __launch_bounds__(1024) void k_slots(const int* __restrict__ tok_e,
                                                const float* __restrict__ tok_w,
                                                int* __restrict__ rows,
                                                float* __restrict__ rw,
                                                int* __restrict__ slot_of,
                                                int* __restrict__ po_g) {
  __shared__ unsigned short rank_s[NASSIGN];
  __shared__ int chunkcnt[128][NE];
  __shared__ int po_s[NE + 1];
  __shared__ int counts_s[NE];
  int tid = threadIdx.x, lane = tid & 63, wave = tid >> 6;
  unsigned long long below = (lane == 0) ? 0ull : ((~0ull) >> (64 - lane));
#pragma unroll
  for (int j = 0; j < 8; ++j) {
    int c = wave * 8 + j;
    int a = c * 64 + lane;
    int ei = tok_e[a];
    int myrank = 0, mycnt = 0;
#pragma unroll
    for (int e = 0; e < NE; ++e) {
      unsigned long long m = __ballot(ei == e);
      if (e == ei) myrank = __popcll(m & below);
      if (lane == e) mycnt = __popcll(m);
    }
    rank_s[a] = (unsigned short)myrank;
    if (lane < NE) chunkcnt[c][lane] = mycnt;
  }
  __syncthreads();
  if (tid < NE) {
    int run = 0;
    for (int c = 0; c < 128; ++c) {
      int v = chunkcnt[c][tid];
      chunkcnt[c][tid] = run;
      run += v;
    }
    counts_s[tid] = run;
  }
  __syncthreads();
  if (tid == 0) {
    int s = 0;
    po_s[0] = 0;
    for (int e = 0; e < NE; ++e) {
      s += ((counts_s[e] + 127) >> 7) << 7;   // pad to 128
      po_s[e + 1] = s;
    }
  }
  __syncthreads();
  if (tid < NE + 1) po_g[tid] = po_s[tid];
  int po8 = po_s[NE];
#pragma unroll
  for (int j = 0; j < 8; ++j) {
    int a = tid + j * 1024;
    int e = tok_e[a];
    int c = a >> 6;
    int slot = po_s[e] + chunkcnt[c][e] + (int)rank_s[a];
    rows[slot] = a >> 1;
    rw[slot] = tok_w[a];
    slot_of[a] = slot;
  }
  // shared-expert segment: slots [po8, po8+NTOK), identity rows, weight 1
  for (int s = tid; s < NTOK; s += 1024) {
    rows[po8 + s] = s;
    rw[po8 + s] = 1.f;
  }
  // pad slots inside expert segments
  for (int s = tid; s < MAXSLOT_E; s += 1024) {
    if (s >= po8) break;
    int e = 0;
#pragma unroll
    for (int i = 1; i < NE; ++i)
      if (s >= po_s[i]) e = i;
    if (s >= po_s[e] + counts_s[e]) { rows[s] = 0; rw[s] = 0.f; }
  }
}

// ---- grouped GEMM (shared = expert 8): 128x128 tile, BK=64, 4 waves, 64KB LDS ----
// 2 blocks/CU; phase (1 barrier): LGKM0 -> 32-MFMA -> BARR -> STG(k+2) ->
// VMCNT(8) -> RD(k+1). WAR-safe: all waves' reads of a buffer are lgkm-DRAINED
// before the barrier that precedes its overwrite.
template <bool UP>
__global__ __launch_bounds__(256, 2) void k_gemm(const unsigned short* __restrict__ A,
                                                 const unsigned short* __restrict__ Be,
                                                 const unsigned short* __restrict__ Bsh,
                                                 const float* __restrict__ be,
                                                 const float* __restrict__ bsh,
                                                 const int* __restrict__ rows,
                                                 const float* __restrict__ rw,
                                                 const int* __restrict__ po,
                                                 unsigned short* __restrict__ OutB,
                                                 float* __restrict__ OutF) {
  __shared__ unsigned short LA[2][128 * 64];
  __shared__ unsigned short LB[2][128 * 64];
  // bijective XCD-chunked swizzle (GRID_G % 8 == 0), rt-major within XCD
  int orig = blockIdx.x;
  int wgid = (orig & 7) * (GRID_G / 8) + (orig >> 3);
  int rt = wgid >> 3, ct = wgid & 7;
  int row0 = rt * 128;
  int po8 = po[NE];
  if (row0 >= po8 + NTOK) return;
  int e = NE;  // shared
  if (row0 < po8) {
    e = 0;
#pragma unroll
    for (int i = 1; i < NE; ++i)
      if (row0 >= po[i]) e = i;
  }
  const unsigned short* Bm = (e < NE) ? Be + (size_t)e * (DM * DH) : Bsh;
  const float* bia = (e < NE) ? be + (size_t)e * (UP ? DH : DM) : bsh;

  int tid = threadIdx.x, lane = tid & 63, w = tid >> 6;
  int wr = w >> 1, wc = w & 1, l15 = lane & 15;
  int s0 = (lane >> 4) ^ (lane & 7);  // kk=0 swizzled slot

  // staging: 1 load/thread/call covers one 32-row quadrant (dest = uniform+lane*16B)
  int st_r = tid >> 3;       // 0..31
  int st_s = tid & 7;
  int grA[4];
  if (UP) {
#pragma unroll
    for (int q = 0; q < 4; ++q) grA[q] = rows[row0 + q * 32 + st_r];
  }

  f32x4 acc[4][4] = {};
  short8 a[4][2], b[4][2];

  auto STG_A = [&](int buf, int q, int kt) {
    int lr = q * 32 + st_r;
    int gk = st_s ^ (lr & 7);
    int grow = UP ? grA[q] : (row0 + lr);
    async_ld16(A + (size_t)grow * 1024 + kt * 64 + gk * 8,
               &LA[buf][lr * 64 + st_s * 8]);
  };
  auto STG_B = [&](int buf, int q, int kt) {
    int lr = q * 32 + st_r;
    int gk = st_s ^ (lr & 7);
    int gcol = ct * 128 + lr;
    async_ld16(Bm + (size_t)gcol * 1024 + kt * 64 + gk * 8,
               &LB[buf][lr * 64 + st_s * 8]);
  };

  int sl[2] = {s0 * 8, (s0 ^ 4) * 8};

  auto RD_A = [&](int buf) {
#pragma unroll
    for (int m4 = 0; m4 < 4; ++m4)
#pragma unroll
      for (int kk = 0; kk < 2; ++kk)
        a[m4][kk] = *(const short8*)(&LA[buf][0] + (wr * 64 + m4 * 16 + l15) * 64 + sl[kk]);
  };
  auto RD_B = [&](int buf) {
#pragma unroll
    for (int n = 0; n < 4; ++n)
#pragma unroll
      for (int kk = 0; kk < 2; ++kk)
        b[n][kk] = *(const short8*)(&LB[buf][0] + (wc * 64 + n * 16 + l15) * 64 + sl[kk]);
  };
  auto MFMA32 = [&]() {
    __builtin_amdgcn_s_setprio(1);
#pragma unroll
    for (int m4 = 0; m4 < 4; ++m4)
#pragma unroll
      for (int n = 0; n < 4; ++n)
#pragma unroll
        for (int kk = 0; kk < 2; ++kk)
          acc[m4][n] = __builtin_amdgcn_mfma_f32_16x16x32_bf16(
              a[m4][kk], b[n][kk], acc[m4][n], 0, 0, 0);
    __builtin_amdgcn_s_setprio(0);
    __builtin_amdgcn_sched_barrier(0);
  };

  // ---- prologue: tile0 -> buf0 (8 loads), tile1 -> buf1 (8 loads)
#pragma unroll
  for (int q = 0; q < 4; ++q) STG_A(0, q, 0);
#pragma unroll
  for (int q = 0; q < 4; ++q) STG_B(0, q, 0);
#pragma unroll
  for (int q = 0; q < 4; ++q) STG_A(1, q, 1);
#pragma unroll
  for (int q = 0; q < 4; ++q) STG_B(1, q, 1);
  VMCNT(8);  // tile0 landed (oldest 8); tile1 in flight
  BARR();
  RD_A(0); RD_B(0);

  // ---- 16 K-tiles, one phase each:
  //   LGKM0 (my reads of buf bf drained) -> MFMA32(tile k from bf) ->
  //   BARR (ALL waves' reads of bf drained) -> STG tile k+2 into bf ->
  //   VMCNT(8) (tile k+1 landed) -> RD frags of buf nb (tile k+1).
  // WAR-safe: buffer overwrite is issued strictly after a barrier that follows
  // every wave's lgkmcnt(0) drain of its reads from that buffer.
#pragma unroll
  for (int k = 0; k < 16; ++k) {
    int bf = k & 1;
    int kt2 = (k + 2) & 15;  // wraps to dummy re-stage of t0/t1 at tail (unused)
    LGKM0();
    MFMA32();
    BARR();
#pragma unroll
    for (int q = 0; q < 4; ++q) STG_A(bf, q, kt2);
#pragma unroll
    for (int q = 0; q < 4; ++q) STG_B(bf, q, kt2);
    VMCNT(8);
    RD_A(bf ^ 1); RD_B(bf ^ 1);
  }
  LGKM0();   // drain tail frag reads (unused garbage from dummy stages)
  VMCNT(0);  // drain wrapped dummy stages before epilogue

  // ---- epilogue
  int gcol0 = ct * 128 + wc * 64;
#pragma unroll
  for (int m = 0; m < 4; ++m) {
    int rbase = row0 + wr * 64 + m * 16 + ((lane >> 4) << 2);
#pragma unroll
    for (int j = 0; j < 4; ++j) {
      int grow = rbase + j;
#pragma unroll
      for (int n = 0; n < 4; ++n) {
        int gc = gcol0 + n * 16 + l15;
        float v = acc[m][n][j] + bia[gc];
        if (UP) {
          v = v / (1.f + __expf(-v));  // silu
          OutB[(size_t)grow * DH + gc] = f2bf(v);
        } else if (e < NE) {
          OutB[(size_t)grow * DM + gc] = f2bf(v * rw[grow]);
        } else {
          OutF[(size_t)(grow - po8) * DM + gc] = v;  // shared -> out fp32
        }
      }
    }
  }
}

// ---------------- final combine: out[t] += YE[s0] + YE[s1] ----------------
__global__ __launch_bounds__(256) void k_combine(float* __restrict__ out,
                                                 const unsigned short* __restrict__ YE,
                                                 const int* __restrict__ slot_of) {
  int t = blockIdx.x;
  int s0 = slot_of[t * 2 + 0], s1 = slot_of[t * 2 + 1];
  int c = threadIdx.x * 4;
  float* op = out + (size_t)t * DM + c;
  float4 o = *(float4*)op;
  ushort4 a = *(const ushort4*)(YE + (size_t)s0 * DM + c);
  ushort4 b = *(const ushort4*)(YE + (size_t)s1 * DM + c);
  o.x += bf2f(a.x) + bf2f(b.x);
  o.y += bf2f(a.y) + bf2f(b.y);
  o.z += bf2f(a.z) + bf2f(b.z);
  o.w += bf2f(a.w) + bf2f(b.w);
  *(float4*)op = o;
}

extern "C" void kernel_launch(void* const* d_in, const int* in_sizes, int n_in,
                              void* d_out, int out_size, void* d_ws, size_t ws_size,
                              hipStream_t stream) {
  const float* x        = (const float*)d_in[0];
  const float* gate_w   = (const float*)d_in[1];
  const float* up_w     = (const float*)d_in[2];
  const float* up_b     = (const float*)d_in[3];
  const float* down_w   = (const float*)d_in[4];
  const float* down_b   = (const float*)d_in[5];
  const float* sh_up_w  = (const float*)d_in[6];
  const float* sh_up_b  = (const float*)d_in[7];
  const float* sh_dn_w  = (const float*)d_in[8];
  const float* sh_dn_b  = (const float*)d_in[9];
  float* out = (float*)d_out;

  char* ws = (char*)d_ws;
  const size_t MB = 1024 * 1024;
  unsigned short* xb   = (unsigned short*)(ws + 0);          // 8 MB
  unsigned short* upT  = (unsigned short*)(ws + 8 * MB);     // 16 MB
  unsigned short* dnT  = (unsigned short*)(ws + 24 * MB);    // 16 MB
  unsigned short* shuT = (unsigned short*)(ws + 40 * MB);    // 2 MB
  unsigned short* shdT = (unsigned short*)(ws + 42 * MB);    // 2 MB
  unsigned short* H    = (unsigned short*)(ws + 44 * MB);    // 26 MB (13312*1024*2)
  char* tail = ws + 44 * MB + (size_t)MAXSLOT_ALL * DH * 2;
  int*   tok_e   = (int*)tail;                tail += NASSIGN * 4;
  float* tok_w   = (float*)tail;              tail += NASSIGN * 4;
  int*   slot_of = (int*)tail;                tail += NASSIGN * 4;
  int*   rows    = (int*)tail;                tail += MAXSLOT_ALL * 4;
  float* rw      = (float*)tail;              tail += MAXSLOT_ALL * 4;
  int*   po      = (int*)tail;                tail += 64;
  unsigned short* YE = (unsigned short*)(ws + 0);  // alias xb+upT (18 MB < 24 MB)

  // 1) one dispatch: weight transposes + fused x-convert/route; then slot sort
  k_prep<<<4608 + NTOK / 4, 256, 0, stream>>>(up_w, down_w, sh_up_w, sh_dn_w,
                                              upT, dnT, shuT, shdT,
                                              x, gate_w, xb, tok_e, tok_w);
  k_slots<<<1, 1024, 0, stream>>>(tok_e, tok_w, rows, rw, slot_of, po);

  // 2) grouped GEMMs (experts 0..7 + shared as 8), 128x128, 2 blocks/CU
  k_gemm<true><<<GRID_G, 256, 0, stream>>>(
      xb, upT, shuT, up_b, sh_up_b, rows, rw, po, H, nullptr);
  k_gemm<false><<<GRID_G, 256, 0, stream>>>(
      H, dnT, shdT, down_b, sh_dn_b, rows, rw, po, YE, out);

  // 3) combine
  k_combine<<<NTOK, 256, 0, stream>>>(out, YE, slot_of);
}

// Round 15
// 139.481 us; speedup vs baseline: 1.0676x; 1.0676x over previous
//
#include <hip/hip_runtime.h>
#include <hip/hip_bf16.h>
#include <cstdint>
#include <cstddef>

// MoE FFN: x[2,2048,1024] fp32, 8 experts top-2 + 1 shared expert.
// R15 = best-of composition:
//  - GEMM: R12's 256x256, BK=64, 8 waves, 2 phases/K-tile, 32-MFMA clusters,
//    counted vmcnt(8) ledger, XCD-chunked swizzle (best measured: 53.4 us).
//  - Prep: R14's single-dispatch fusion (18 weight transposes + x-cvt/route).
//  - Slots padded to 256; combine unchanged.

#define NTOK 4096
#define DM 1024
#define DH 1024
#define NE 8
#define MAXSLOT_E 10240           // 8192 assignments + 8*256 padding (worst case)
#define MAXSLOT_ALL (MAXSLOT_E + NTOK)  // + shared segment (4096) = 14336
#define NASSIGN (NTOK * 2)
#define NRT2 (MAXSLOT_ALL / 256)  // 56 row tiles
#define GRID_G (NRT2 * 4)         // 224 blocks (4 col tiles), 224 % 8 == 0

typedef __attribute__((ext_vector_type(8))) short short8;
typedef __attribute__((ext_vector_type(8))) unsigned short ushort8v;
typedef __attribute__((ext_vector_type(4))) float f32x4;

__device__ __forceinline__ unsigned short f2bf(float f) {
  uint32_t u = __float_as_uint(f);
  return (unsigned short)((u + 0x7FFFu + ((u >> 16) & 1u)) >> 16);  // RNE
}
__device__ __forceinline__ float bf2f(unsigned short h) {
  return __uint_as_float(((uint32_t)h) << 16);
}

__device__ __forceinline__ void async_ld16(const void* g, void* l) {
  __builtin_amdgcn_global_load_lds(
      (const __attribute__((address_space(1))) void*)g,
      (__attribute__((address_space(3))) void*)l, 16, 0, 0);
}

__device__ __forceinline__ void BARR() {
  asm volatile("" ::: "memory");
  __builtin_amdgcn_s_barrier();
  asm volatile("" ::: "memory");
}
__device__ __forceinline__ void LGKM0() {
  asm volatile("s_waitcnt lgkmcnt(0)" ::: "memory");
  __builtin_amdgcn_sched_barrier(0);
}
#define VMCNT(n) asm volatile("s_waitcnt vmcnt(" #n ")" ::: "memory")

// ---- ONE dispatch: 18 weight-matrix transposes (blocks 0..4607) + fused
//      x-convert/route (blocks 4608..5631). Independent work, runs concurrently.
__global__ __launch_bounds__(256) void k_prep(const float* __restrict__ up_w,
                                              const float* __restrict__ down_w,
                                              const float* __restrict__ sh_up,
                                              const float* __restrict__ sh_dn,
                                              unsigned short* __restrict__ upT,
                                              unsigned short* __restrict__ dnT,
                                              unsigned short* __restrict__ shuT,
                                              unsigned short* __restrict__ shdT,
                                              const float* __restrict__ x,
                                              const float* __restrict__ gw,
                                              unsigned short* __restrict__ xb,
                                              int* __restrict__ tok_e,
                                              float* __restrict__ tok_w) {
  __shared__ float tile[64][65];
  int id = blockIdx.x;
  if (id < 4608) {
    int z = id >> 8, rem = id & 255;
    int r0 = (rem >> 4) * 64, c0 = (rem & 15) * 64;
    const float* S;
    unsigned short* D;
    if (z < 8)        { S = up_w   + (size_t)z * (DM * DH);       D = upT + (size_t)z * (DM * DH); }
    else if (z < 16)  { S = down_w + (size_t)(z - 8) * (DM * DH); D = dnT + (size_t)(z - 8) * (DM * DH); }
    else if (z == 16) { S = sh_up;  D = shuT; }
    else              { S = sh_dn;  D = shdT; }
    int t = threadIdx.x;
    int fc = (t & 15) * 4, rr = t >> 4;
#pragma unroll
    for (int i = 0; i < 4; ++i) {
      int r = rr + i * 16;
      float4 v = *(const float4*)&S[(size_t)(r0 + r) * 1024 + c0 + fc];
      tile[r][fc + 0] = v.x; tile[r][fc + 1] = v.y;
      tile[r][fc + 2] = v.z; tile[r][fc + 3] = v.w;
    }
    __syncthreads();
    int c = t >> 2;
    int rs = (t & 3) * 16;
#pragma unroll
    for (int j = 0; j < 2; ++j) {
      int rb = rs + j * 8;
      ushort8v o;
#pragma unroll
      for (int k = 0; k < 8; ++k) o[k] = f2bf(tile[rb + k][c]);
      *(ushort8v*)&D[(size_t)(c0 + c) * 1024 + r0 + rb] = o;
    }
  } else {
    int wave = threadIdx.x >> 6, lane = threadIdx.x & 63;
    int t = (id - 4608) * 4 + wave;
    const float4* xt = (const float4*)(x + (size_t)t * DM);
    unsigned short* xbt = xb + (size_t)t * DM;
    float acc[NE];
#pragma unroll
    for (int e = 0; e < NE; ++e) acc[e] = 0.f;
#pragma unroll
    for (int c = 0; c < 4; ++c) {
      int idx = lane + c * 64;
      float4 v = xt[idx];
      ushort4 o;
      o.x = f2bf(v.x); o.y = f2bf(v.y); o.z = f2bf(v.z); o.w = f2bf(v.w);
      *(ushort4*)(xbt + idx * 4) = o;
#pragma unroll
      for (int e = 0; e < NE; ++e) {
        float4 g = ((const float4*)(gw + (size_t)e * DM))[idx];
        acc[e] += v.x * g.x + v.y * g.y + v.z * g.z + v.w * g.w;
      }
    }
#pragma unroll
    for (int e = 0; e < NE; ++e) {
#pragma unroll
      for (int off = 32; off; off >>= 1) acc[e] += __shfl_xor(acc[e], off, 64);
    }
    if (lane == 0) {
      float m = acc[0];
#pragma unroll
      for (int e = 1; e < NE; ++e) m = fmaxf(m, acc[e]);
      float p[NE], s = 0.f;
#pragma unroll
      for (int e = 0; e < NE; ++e) { p[e] = __expf(acc[e] - m); s += p[e]; }
#pragma unroll
      for (int e = 0; e < NE; ++e) p[e] /= s;
      int i0 = 0;
#pragma unroll
      for (int e = 1; e < NE; ++e) if (p[e] > p[i0]) i0 = e;
      int i1 = (i0 == 0) ? 1 : 0;
#pragma unroll
      for (int e = 0; e < NE; ++e) if (e != i0 && p[e] > p[i1]) i1 = e;
      float w0 = p[i0], w1 = p[i1];
      float dnm = w0 + w1 + 1e-20f;
      w0 /= dnm; w1 /= dnm;
      tok_e[t * 2 + 0] = i0; tok_e[t * 2 + 1] = i1;
      tok_w[t * 2 + 0] = w0; tok_w[t * 2 + 1] = w1;
    }
  }
}

// --------- slot assignment: single block, ballot-based stable counting sort ---------
// experts padded to 256 rows (GEMM tile = 256)
__global__ __launch_bounds__(1024) void k_slots(const int* __restrict__ tok_e,
                                                const float* __restrict__ tok_w,
                                                int* __restrict__ rows,
                                                float* __restrict__ rw,
                                                int* __restrict__ slot_of,
                                                int* __restrict__ po_g) {
  __shared__ unsigned short rank_s[NASSIGN];
  __shared__ int chunkcnt[128][NE];
  __shared__ int po_s[NE + 1];
  __shared__ int counts_s[NE];
  int tid = threadIdx.x, lane = tid & 63, wave = tid >> 6;
  unsigned long long below = (lane == 0) ? 0ull : ((~0ull) >> (64 - lane));
#pragma unroll
  for (int j = 0; j < 8; ++j) {
    int c = wave * 8 + j;
    int a = c * 64 + lane;
    int ei = tok_e[a];
    int myrank = 0, mycnt = 0;
#pragma unroll
    for (int e = 0; e < NE; ++e) {
      unsigned long long m = __ballot(ei == e);
      if (e == ei) myrank = __popcll(m & below);
      if (lane == e) mycnt = __popcll(m);
    }
    rank_s[a] = (unsigned short)myrank;
    if (lane < NE) chunkcnt[c][lane] = mycnt;
  }
  __syncthreads();
  if (tid < NE) {
    int run = 0;
    for (int c = 0; c < 128; ++c) {
      int v = chunkcnt[c][tid];
      chunkcnt[c][tid] = run;
      run += v;
    }
    counts_s[tid] = run;
  }
  __syncthreads();
  if (tid == 0) {
    int s = 0;
    po_s[0] = 0;
    for (int e = 0; e < NE; ++e) {
      s += ((counts_s[e] + 255) >> 8) << 8;   // pad to 256
      po_s[e + 1] = s;
    }
  }
  __syncthreads();
  if (tid < NE + 1) po_g[tid] = po_s[tid];
  int po8 = po_s[NE];
#pragma unroll
  for (int j = 0; j < 8; ++j) {
    int a = tid + j * 1024;
    int e = tok_e[a];
    int c = a >> 6;
    int slot = po_s[e] + chunkcnt[c][e] + (int)rank_s[a];
    rows[slot] = a >> 1;
    rw[slot] = tok_w[a];
    slot_of[a] = slot;
  }
  // shared-expert segment: slots [po8, po8+NTOK), identity rows, weight 1
  for (int s = tid; s < NTOK; s += 1024) {
    rows[po8 + s] = s;
    rw[po8 + s] = 1.f;
  }
  // pad slots inside expert segments
  for (int s = tid; s < MAXSLOT_E; s += 1024) {
    if (s >= po8) break;
    int e = 0;
#pragma unroll
    for (int i = 1; i < NE; ++i)
      if (s >= po_s[i]) e = i;
    if (s >= po_s[e] + counts_s[e]) { rows[s] = 0; rw[s] = 0.f; }
  }
}

// ---- grouped GEMM (shared = expert 8): 256x256 tile, BK=64, 8 waves ----
// 2 phases / K-tile, 32-MFMA clusters, 32 barriers total; VMCNT(8) precedes
// next-buffer frag reads (ledger provably covers staging).  [R12 verbatim]
template <bool UP>
__global__ __launch_bounds__(512, 2) void k_gemm(const unsigned short* __restrict__ A,
                                                 const unsigned short* __restrict__ Be,
                                                 const unsigned short* __restrict__ Bsh,
                                                 const float* __restrict__ be,
                                                 const float* __restrict__ bsh,
                                                 const int* __restrict__ rows,
                                                 const float* __restrict__ rw,
                                                 const int* __restrict__ po,
                                                 unsigned short* __restrict__ OutB,
                                                 float* __restrict__ OutF) {
  __shared__ unsigned short LA[2][2][128 * 64];
  __shared__ unsigned short LB[2][2][128 * 64];
  // bijective XCD-chunked swizzle (GRID_G % 8 == 0), rt-major within XCD
  int orig = blockIdx.x;
  int wgid = (orig & 7) * (GRID_G / 8) + (orig >> 3);
  int rt = wgid >> 2, ct = wgid & 3;
  int row0 = rt * 256;
  int po8 = po[NE];
  if (row0 >= po8 + NTOK) return;
  int e = NE;  // shared
  if (row0 < po8) {
    e = 0;
#pragma unroll
    for (int i = 1; i < NE; ++i)
      if (row0 >= po[i]) e = i;
  }
  const unsigned short* Bm = (e < NE) ? Be + (size_t)e * (DM * DH) : Bsh;
  const float* bia = (e < NE) ? be + (size_t)e * (UP ? DH : DM) : bsh;

  int tid = threadIdx.x, lane = tid & 63, w = tid >> 6;
  int wr = w >> 2, wc = w & 3, l15 = lane & 15;
  int s0 = (lane >> 4) ^ (lane & 7);  // kk=0 swizzled slot

  // staging: 1 load/thread/call, one 64-row quadrant; dest = uniform + lane*16B
  int st_r = tid >> 3;       // 0..63
  int st_s = tid & 7;
  int grA[2][2];
  if (UP) {
#pragma unroll
    for (int h = 0; h < 2; ++h)
#pragma unroll
      for (int q = 0; q < 2; ++q)
        grA[h][q] = rows[row0 + h * 128 + q * 64 + st_r];
  }

  f32x4 acc[8][4] = {};
  short8 aE[4][2], aO[4][2], b[4][2];

  auto STG_A = [&](int buf, int h, int q, int kt) {
    int lr = q * 64 + st_r;
    int gk = st_s ^ (lr & 7);
    int grow = UP ? grA[h][q] : (row0 + h * 128 + lr);
    async_ld16(A + (size_t)grow * 1024 + kt * 64 + gk * 8,
               &LA[buf][h][lr * 64 + st_s * 8]);
  };
  auto STG_B = [&](int buf, int h, int q, int kt) {
    int lr = q * 64 + st_r;
    int gk = st_s ^ (lr & 7);
    int gcol = ct * 256 + h * 128 + lr;
    async_ld16(Bm + (size_t)gcol * 1024 + kt * 64 + gk * 8,
               &LB[buf][h][lr * 64 + st_s * 8]);
  };

  const unsigned short* Ab_[2] = {&LA[0][wr][0], &LA[1][wr][0]};
  const unsigned short* Bb_[2] = {&LB[0][wc >> 1][0], &LB[1][wc >> 1][0]};
  int brow0 = (wc & 1) * 64 + l15;
  int sl[2] = {s0 * 8, (s0 ^ 4) * 8};

  auto RD_A = [&](int buf, int mq, short8 (*dst)[2]) {
#pragma unroll
    for (int m4 = 0; m4 < 4; ++m4)
#pragma unroll
      for (int kk = 0; kk < 2; ++kk)
        dst[m4][kk] = *(const short8*)(Ab_[buf] + (mq * 64 + m4 * 16 + l15) * 64 + sl[kk]);
  };
  auto RD_B = [&](int buf, int np) {
#pragma unroll
    for (int n2 = 0; n2 < 2; ++n2)
#pragma unroll
      for (int kk = 0; kk < 2; ++kk)
        b[np * 2 + n2][kk] =
            *(const short8*)(Bb_[buf] + (brow0 + (np * 2 + n2) * 16) * 64 + sl[kk]);
  };
  // 32-MFMA cluster: one A row-quadrant (mq) x ALL 4 n-frags x 2 kk
  auto MFMA32 = [&](short8 (*am)[2], int mq) {
    __builtin_amdgcn_s_setprio(1);
#pragma unroll
    for (int m4 = 0; m4 < 4; ++m4)
#pragma unroll
      for (int n = 0; n < 4; ++n)
#pragma unroll
        for (int kk = 0; kk < 2; ++kk)
          acc[mq * 4 + m4][n] = __builtin_amdgcn_mfma_f32_16x16x32_bf16(
              am[m4][kk], b[n][kk], acc[mq * 4 + m4][n], 0, 0, 0);
    __builtin_amdgcn_s_setprio(0);
    __builtin_amdgcn_sched_barrier(0);
  };

  // ---- prologue: tile0 -> buf0, tile1 -> buf1; frags for tile0
  STG_A(0, 0, 0, 0); STG_A(0, 1, 0, 0); STG_A(0, 0, 1, 0); STG_A(0, 1, 1, 0);
  STG_B(0, 0, 0, 0); STG_B(0, 0, 1, 0); STG_B(0, 1, 0, 0); STG_B(0, 1, 1, 0);
  STG_A(1, 0, 0, 1); STG_A(1, 1, 0, 1); STG_A(1, 0, 1, 1); STG_A(1, 1, 1, 1);
  STG_B(1, 0, 0, 1); STG_B(1, 0, 1, 1); STG_B(1, 1, 0, 1); STG_B(1, 1, 1, 1);
  VMCNT(8);  // tile0 landed (oldest 8); tile1 in flight
  BARR();
  RD_A(0, 0, aE); RD_B(0, 0); RD_B(0, 1);  // tile0 ph1 frags

  // ---- 8 iterations x 2 tiles x 2 phases.
  // ph1: MFMA(mq0) | RD aO(bf q1) | STG bf: A-q0 x2, B-h0 x2 | BARR
  // ph2: MFMA(mq1) | STG bf: A-q1 x2, B-h1 x2 | VMCNT(8) | RD nb: aE + b | BARR
  for (int it = 0; it < 8; ++it) {
    int tn = (2 * it + 2) & 15, un = (2 * it + 3) & 15;
#pragma unroll
    for (int half = 0; half < 2; ++half) {
      int bf = half, nb = half ^ 1;
      int kt = half ? un : tn;
      // ph1
      LGKM0(); MFMA32(aE, 0);
      RD_A(bf, 1, aO);
      STG_A(bf, 0, 0, kt); STG_A(bf, 1, 0, kt);
      STG_B(bf, 0, 0, kt); STG_B(bf, 0, 1, kt);
      BARR();
      // ph2
      LGKM0(); MFMA32(aO, 1);
      STG_A(bf, 0, 1, kt); STG_A(bf, 1, 1, kt);
      STG_B(bf, 1, 0, kt); STG_B(bf, 1, 1, kt);
      VMCNT(8);  // nb's tile fully landed before its frag reads below
      RD_A(nb, 0, aE); RD_B(nb, 0); RD_B(nb, 1);
      BARR();
    }
  }
  VMCNT(0);  // drain wrapped dummy stages before epilogue

  // ---- epilogue
  int gcol0 = ct * 256 + wc * 64;
#pragma unroll
  for (int m = 0; m < 8; ++m) {
    int rbase = row0 + wr * 128 + m * 16 + ((lane >> 4) << 2);
#pragma unroll
    for (int j = 0; j < 4; ++j) {
      int grow = rbase + j;
#pragma unroll
      for (int n = 0; n < 4; ++n) {
        int gc = gcol0 + n * 16 + l15;
        float v = acc[m][n][j] + bia[gc];
        if (UP) {
          v = v / (1.f + __expf(-v));  // silu
          OutB[(size_t)grow * DH + gc] = f2bf(v);
        } else if (e < NE) {
          OutB[(size_t)grow * DM + gc] = f2bf(v * rw[grow]);
        } else {
          OutF[(size_t)(grow - po8) * DM + gc] = v;  // shared -> out fp32
        }
      }
    }
  }
}

// ---------------- final combine: out[t] += YE[s0] + YE[s1] ----------------
__global__ __launch_bounds__(256) void k_combine(float* __restrict__ out,
                                                 const unsigned short* __restrict__ YE,
                                                 const int* __restrict__ slot_of) {
  int t = blockIdx.x;
  int s0 = slot_of[t * 2 + 0], s1 = slot_of[t * 2 + 1];
  int c = threadIdx.x * 4;
  float* op = out + (size_t)t * DM + c;
  float4 o = *(float4*)op;
  ushort4 a = *(const ushort4*)(YE + (size_t)s0 * DM + c);
  ushort4 b = *(const ushort4*)(YE + (size_t)s1 * DM + c);
  o.x += bf2f(a.x) + bf2f(b.x);
  o.y += bf2f(a.y) + bf2f(b.y);
  o.z += bf2f(a.z) + bf2f(b.z);
  o.w += bf2f(a.w) + bf2f(b.w);
  *(float4*)op = o;
}

extern "C" void kernel_launch(void* const* d_in, const int* in_sizes, int n_in,
                              void* d_out, int out_size, void* d_ws, size_t ws_size,
                              hipStream_t stream) {
  const float* x        = (const float*)d_in[0];
  const float* gate_w   = (const float*)d_in[1];
  const float* up_w     = (const float*)d_in[2];
  const float* up_b     = (const float*)d_in[3];
  const float* down_w   = (const float*)d_in[4];
  const float* down_b   = (const float*)d_in[5];
  const float* sh_up_w  = (const float*)d_in[6];
  const float* sh_up_b  = (const float*)d_in[7];
  const float* sh_dn_w  = (const float*)d_in[8];
  const float* sh_dn_b  = (const float*)d_in[9];
  float* out = (float*)d_out;

  char* ws = (char*)d_ws;
  const size_t MB = 1024 * 1024;
  unsigned short* xb   = (unsigned short*)(ws + 0);          // 8 MB
  unsigned short* upT  = (unsigned short*)(ws + 8 * MB);     // 16 MB
  unsigned short* dnT  = (unsigned short*)(ws + 24 * MB);    // 16 MB
  unsigned short* shuT = (unsigned short*)(ws + 40 * MB);    // 2 MB
  unsigned short* shdT = (unsigned short*)(ws + 42 * MB);    // 2 MB
  unsigned short* H    = (unsigned short*)(ws + 44 * MB);    // 28 MB (14336*1024*2)
  char* tail = ws + 44 * MB + (size_t)MAXSLOT_ALL * DH * 2;
  int*   tok_e   = (int*)tail;                tail += NASSIGN * 4;
  float* tok_w   = (float*)tail;              tail += NASSIGN * 4;
  int*   slot_of = (int*)tail;                tail += NASSIGN * 4;
  int*   rows    = (int*)tail;                tail += MAXSLOT_ALL * 4;
  float* rw      = (float*)tail;              tail += MAXSLOT_ALL * 4;
  int*   po      = (int*)tail;                tail += 64;
  unsigned short* YE = (unsigned short*)(ws + 0);  // alias xb+upT (20 MB < 24 MB)

  // 1) one dispatch: weight transposes + fused x-convert/route; then slot sort
  k_prep<<<4608 + NTOK / 4, 256, 0, stream>>>(up_w, down_w, sh_up_w, sh_dn_w,
                                              upT, dnT, shuT, shdT,
                                              x, gate_w, xb, tok_e, tok_w);
  k_slots<<<1, 1024, 0, stream>>>(tok_e, tok_w, rows, rw, slot_of, po);

  // 2) grouped GEMMs (experts 0..7 + shared as 8), 256x256, 2-phase clusters
  k_gemm<true><<<GRID_G, 512, 0, stream>>>(
      xb, upT, shuT, up_b, sh_up_b, rows, rw, po, H, nullptr);
  k_gemm<false><<<GRID_G, 512, 0, stream>>>(
      H, dnT, shdT, down_b, sh_dn_b, rows, rw, po, YE, out);

  // 3) combine
  k_combine<<<NTOK, 256, 0, stream>>>(out, YE, slot_of);
}

// Round 16
// 139.440 us; speedup vs baseline: 1.0679x; 1.0003x over previous
//
#include <hip/hip_runtime.h>
#include <hip/hip_bf16.h>
#include <cstdint>
#include <cstddef>

// MoE FFN: x[2,2048,1024] fp32, 8 experts top-2 + 1 shared expert.
// R15: best-of composition (256² 2-phase GEMM + fused prep) = 139.5 us.
// R16: counted lgkmcnt (the never-ported m201 piece): split 32-MFMA clusters
//      into 2x16 with lgkmcnt(8)/(4) -> lgkmcnt(0), reads issued in pinned
//      groups (sched_barrier between), exploiting in-order DS return. MFMA
//      starts when 2/3 of frags landed -> LDS drain overlaps MFMA pipe.

#define NTOK 4096
#define DM 1024
#define DH 1024
#define NE 8
#define MAXSLOT_E 10240           // 8192 assignments + 8*256 padding (worst case)
#define MAXSLOT_ALL (MAXSLOT_E + NTOK)  // + shared segment (4096) = 14336
#define NASSIGN (NTOK * 2)
#define NRT2 (MAXSLOT_ALL / 256)  // 56 row tiles
#define GRID_G (NRT2 * 4)         // 224 blocks (4 col tiles), 224 % 8 == 0

typedef __attribute__((ext_vector_type(8))) short short8;
typedef __attribute__((ext_vector_type(8))) unsigned short ushort8v;
typedef __attribute__((ext_vector_type(4))) float f32x4;

__device__ __forceinline__ unsigned short f2bf(float f) {
  uint32_t u = __float_as_uint(f);
  return (unsigned short)((u + 0x7FFFu + ((u >> 16) & 1u)) >> 16);  // RNE
}
__device__ __forceinline__ float bf2f(unsigned short h) {
  return __uint_as_float(((uint32_t)h) << 16);
}

__device__ __forceinline__ void async_ld16(const void* g, void* l) {
  __builtin_amdgcn_global_load_lds(
      (const __attribute__((address_space(1))) void*)g,
      (__attribute__((address_space(3))) void*)l, 16, 0, 0);
}

__device__ __forceinline__ void BARR() {
  asm volatile("" ::: "memory");
  __builtin_amdgcn_s_barrier();
  asm volatile("" ::: "memory");
}
#define SBAR() __builtin_amdgcn_sched_barrier(0)
#define LGKM(n) do { asm volatile("s_waitcnt lgkmcnt(" #n ")" ::: "memory"); SBAR(); } while (0)
#define VMCNT(n) asm volatile("s_waitcnt vmcnt(" #n ")" ::: "memory")

// ---- ONE dispatch: 18 weight-matrix transposes (blocks 0..4607) + fused
//      x-convert/route (blocks 4608..5631).
__global__ __launch_bounds__(256) void k_prep(const float* __restrict__ up_w,
                                              const float* __restrict__ down_w,
                                              const float* __restrict__ sh_up,
                                              const float* __restrict__ sh_dn,
                                              unsigned short* __restrict__ upT,
                                              unsigned short* __restrict__ dnT,
                                              unsigned short* __restrict__ shuT,
                                              unsigned short* __restrict__ shdT,
                                              const float* __restrict__ x,
                                              const float* __restrict__ gw,
                                              unsigned short* __restrict__ xb,
                                              int* __restrict__ tok_e,
                                              float* __restrict__ tok_w) {
  __shared__ float tile[64][65];
  int id = blockIdx.x;
  if (id < 4608) {
    int z = id >> 8, rem = id & 255;
    int r0 = (rem >> 4) * 64, c0 = (rem & 15) * 64;
    const float* S;
    unsigned short* D;
    if (z < 8)        { S = up_w   + (size_t)z * (DM * DH);       D = upT + (size_t)z * (DM * DH); }
    else if (z < 16)  { S = down_w + (size_t)(z - 8) * (DM * DH); D = dnT + (size_t)(z - 8) * (DM * DH); }
    else if (z == 16) { S = sh_up;  D = shuT; }
    else              { S = sh_dn;  D = shdT; }
    int t = threadIdx.x;
    int fc = (t & 15) * 4, rr = t >> 4;
#pragma unroll
    for (int i = 0; i < 4; ++i) {
      int r = rr + i * 16;
      float4 v = *(const float4*)&S[(size_t)(r0 + r) * 1024 + c0 + fc];
      tile[r][fc + 0] = v.x; tile[r][fc + 1] = v.y;
      tile[r][fc + 2] = v.z; tile[r][fc + 3] = v.w;
    }
    __syncthreads();
    int c = t >> 2;
    int rs = (t & 3) * 16;
#pragma unroll
    for (int j = 0; j < 2; ++j) {
      int rb = rs + j * 8;
      ushort8v o;
#pragma unroll
      for (int k = 0; k < 8; ++k) o[k] = f2bf(tile[rb + k][c]);
      *(ushort8v*)&D[(size_t)(c0 + c) * 1024 + r0 + rb] = o;
    }
  } else {
    int wave = threadIdx.x >> 6, lane = threadIdx.x & 63;
    int t = (id - 4608) * 4 + wave;
    const float4* xt = (const float4*)(x + (size_t)t * DM);
    unsigned short* xbt = xb + (size_t)t * DM;
    float acc[NE];
#pragma unroll
    for (int e = 0; e < NE; ++e) acc[e] = 0.f;
#pragma unroll
    for (int c = 0; c < 4; ++c) {
      int idx = lane + c * 64;
      float4 v = xt[idx];
      ushort4 o;
      o.x = f2bf(v.x); o.y = f2bf(v.y); o.z = f2bf(v.z); o.w = f2bf(v.w);
      *(ushort4*)(xbt + idx * 4) = o;
#pragma unroll
      for (int e = 0; e < NE; ++e) {
        float4 g = ((const float4*)(gw + (size_t)e * DM))[idx];
        acc[e] += v.x * g.x + v.y * g.y + v.z * g.z + v.w * g.w;
      }
    }
#pragma unroll
    for (int e = 0; e < NE; ++e) {
#pragma unroll
      for (int off = 32; off; off >>= 1) acc[e] += __shfl_xor(acc[e], off, 64);
    }
    if (lane == 0) {
      float m = acc[0];
#pragma unroll
      for (int e = 1; e < NE; ++e) m = fmaxf(m, acc[e]);
      float p[NE], s = 0.f;
#pragma unroll
      for (int e = 0; e < NE; ++e) { p[e] = __expf(acc[e] - m); s += p[e]; }
#pragma unroll
      for (int e = 0; e < NE; ++e) p[e] /= s;
      int i0 = 0;
#pragma unroll
      for (int e = 1; e < NE; ++e) if (p[e] > p[i0]) i0 = e;
      int i1 = (i0 == 0) ? 1 : 0;
#pragma unroll
      for (int e = 0; e < NE; ++e) if (e != i0 && p[e] > p[i1]) i1 = e;
      float w0 = p[i0], w1 = p[i1];
      float dnm = w0 + w1 + 1e-20f;
      w0 /= dnm; w1 /= dnm;
      tok_e[t * 2 + 0] = i0; tok_e[t * 2 + 1] = i1;
      tok_w[t * 2 + 0] = w0; tok_w[t * 2 + 1] = w1;
    }
  }
}

// --------- slot assignment: single block, ballot-based stable counting sort ---------
__global__ __launch_bounds__(1024) void k_slots(const int* __restrict__ tok_e,
                                                const float* __restrict__ tok_w,
                                                int* __restrict__ rows,
                                                float* __restrict__ rw,
                                                int* __restrict__ slot_of,
                                                int* __restrict__ po_g) {
  __shared__ unsigned short rank_s[NASSIGN];
  __shared__ int chunkcnt[128][NE];
  __shared__ int po_s[NE + 1];
  __shared__ int counts_s[NE];
  int tid = threadIdx.x, lane = tid & 63, wave = tid >> 6;
  unsigned long long below = (lane == 0) ? 0ull : ((~0ull) >> (64 - lane));
#pragma unroll
  for (int j = 0; j < 8; ++j) {
    int c = wave * 8 + j;
    int a = c * 64 + lane;
    int ei = tok_e[a];
    int myrank = 0, mycnt = 0;
#pragma unroll
    for (int e = 0; e < NE; ++e) {
      unsigned long long m = __ballot(ei == e);
      if (e == ei) myrank = __popcll(m & below);
      if (lane == e) mycnt = __popcll(m);
    }
    rank_s[a] = (unsigned short)myrank;
    if (lane < NE) chunkcnt[c][lane] = mycnt;
  }
  __syncthreads();
  if (tid < NE) {
    int run = 0;
    for (int c = 0; c < 128; ++c) {
      int v = chunkcnt[c][tid];
      chunkcnt[c][tid] = run;
      run += v;
    }
    counts_s[tid] = run;
  }
  __syncthreads();
  if (tid == 0) {
    int s = 0;
    po_s[0] = 0;
    for (int e = 0; e < NE; ++e) {
      s += ((counts_s[e] + 255) >> 8) << 8;   // pad to 256
      po_s[e + 1] = s;
    }
  }
  __syncthreads();
  if (tid < NE + 1) po_g[tid] = po_s[tid];
  int po8 = po_s[NE];
#pragma unroll
  for (int j = 0; j < 8; ++j) {
    int a = tid + j * 1024;
    int e = tok_e[a];
    int c = a >> 6;
    int slot = po_s[e] + chunkcnt[c][e] + (int)rank_s[a];
    rows[slot] = a >> 1;
    rw[slot] = tok_w[a];
    slot_of[a] = slot;
  }
  for (int s = tid; s < NTOK; s += 1024) {
    rows[po8 + s] = s;
    rw[po8 + s] = 1.f;
  }
  for (int s = tid; s < MAXSLOT_E; s += 1024) {
    if (s >= po8) break;
    int e = 0;
#pragma unroll
    for (int i = 1; i < NE; ++i)
      if (s >= po_s[i]) e = i;
    if (s >= po_s[e] + counts_s[e]) { rows[s] = 0; rw[s] = 0.f; }
  }
}

// ---- grouped GEMM (shared = expert 8): 256x256 tile, BK=64, 8 waves ----
// 2 phases / K-tile; counted-lgkm sub-clusters (2x16 MFMA per phase).
template <bool UP>
__global__ __launch_bounds__(512, 2) void k_gemm(const unsigned short* __restrict__ A,
                                                 const unsigned short* __restrict__ Be,
                                                 const unsigned short* __restrict__ Bsh,
                                                 const float* __restrict__ be,
                                                 const float* __restrict__ bsh,
                                                 const int* __restrict__ rows,
                                                 const float* __restrict__ rw,
                                                 const int* __restrict__ po,
                                                 unsigned short* __restrict__ OutB,
                                                 float* __restrict__ OutF) {
  __shared__ unsigned short LA[2][2][128 * 64];
  __shared__ unsigned short LB[2][2][128 * 64];
  int orig = blockIdx.x;
  int wgid = (orig & 7) * (GRID_G / 8) + (orig >> 3);
  int rt = wgid >> 2, ct = wgid & 3;
  int row0 = rt * 256;
  int po8 = po[NE];
  if (row0 >= po8 + NTOK) return;
  int e = NE;  // shared
  if (row0 < po8) {
    e = 0;
#pragma unroll
    for (int i = 1; i < NE; ++i)
      if (row0 >= po[i]) e = i;
  }
  const unsigned short* Bm = (e < NE) ? Be + (size_t)e * (DM * DH) : Bsh;
  const float* bia = (e < NE) ? be + (size_t)e * (UP ? DH : DM) : bsh;

  int tid = threadIdx.x, lane = tid & 63, w = tid >> 6;
  int wr = w >> 2, wc = w & 3, l15 = lane & 15;
  int s0 = (lane >> 4) ^ (lane & 7);  // kk=0 swizzled slot

  int st_r = tid >> 3;       // 0..63
  int st_s = tid & 7;
  int grA[2][2];
  if (UP) {
#pragma unroll
    for (int h = 0; h < 2; ++h)
#pragma unroll
      for (int q = 0; q < 2; ++q)
        grA[h][q] = rows[row0 + h * 128 + q * 64 + st_r];
  }

  f32x4 acc[8][4] = {};
  short8 aE[4][2], aO[4][2], b[4][2];

  auto STG_A = [&](int buf, int h, int q, int kt) {
    int lr = q * 64 + st_r;
    int gk = st_s ^ (lr & 7);
    int grow = UP ? grA[h][q] : (row0 + h * 128 + lr);
    async_ld16(A + (size_t)grow * 1024 + kt * 64 + gk * 8,
               &LA[buf][h][lr * 64 + st_s * 8]);
  };
  auto STG_B = [&](int buf, int h, int q, int kt) {
    int lr = q * 64 + st_r;
    int gk = st_s ^ (lr & 7);
    int gcol = ct * 256 + h * 128 + lr;
    async_ld16(Bm + (size_t)gcol * 1024 + kt * 64 + gk * 8,
               &LB[buf][h][lr * 64 + st_s * 8]);
  };

  const unsigned short* Ab_[2] = {&LA[0][wr][0], &LA[1][wr][0]};
  const unsigned short* Bb_[2] = {&LB[0][wc >> 1][0], &LB[1][wc >> 1][0]};
  int brow0 = (wc & 1) * 64 + l15;
  int sl[2] = {s0 * 8, (s0 ^ 4) * 8};

  // read groups (order pinned by SBAR at call sites; in-order DS return):
  auto RD_Ax = [&](int buf, int mq, short8 (*dst)[2], int m4lo, int m4hi) {
#pragma unroll
    for (int m4 = 0; m4 < 4; ++m4) {
      if (m4 < m4lo || m4 > m4hi) continue;
#pragma unroll
      for (int kk = 0; kk < 2; ++kk)
        dst[m4][kk] = *(const short8*)(Ab_[buf] + (mq * 64 + m4 * 16 + l15) * 64 + sl[kk]);
    }
  };
  auto RD_B2 = [&](int buf, int np) {  // 8 reads: b[np*2], b[np*2+1]
#pragma unroll
    for (int n2 = 0; n2 < 2; ++n2)
#pragma unroll
      for (int kk = 0; kk < 2; ++kk)
        b[np * 2 + n2][kk] =
            *(const short8*)(Bb_[buf] + (brow0 + (np * 2 + n2) * 16) * 64 + sl[kk]);
  };
  // 16-MFMA sub-cluster over n range [nlo, nhi], all m4, both kk
  auto MFMA_N = [&](short8 (*am)[2], int mq, int nlo, int nhi) {
    __builtin_amdgcn_s_setprio(1);
#pragma unroll
    for (int m4 = 0; m4 < 4; ++m4)
#pragma unroll
      for (int n = 0; n < 4; ++n) {
        if (n < nlo || n > nhi) continue;
#pragma unroll
        for (int kk = 0; kk < 2; ++kk)
          acc[mq * 4 + m4][n] = __builtin_amdgcn_mfma_f32_16x16x32_bf16(
              am[m4][kk], b[n][kk], acc[mq * 4 + m4][n], 0, 0, 0);
      }
    __builtin_amdgcn_s_setprio(0);
    SBAR();
  };
  // 16-MFMA sub-cluster over m4 range, all n
  auto MFMA_M = [&](short8 (*am)[2], int mq, int mlo, int mhi) {
    __builtin_amdgcn_s_setprio(1);
#pragma unroll
    for (int m4 = 0; m4 < 4; ++m4) {
      if (m4 < mlo || m4 > mhi) continue;
#pragma unroll
      for (int n = 0; n < 4; ++n)
#pragma unroll
        for (int kk = 0; kk < 2; ++kk)
          acc[mq * 4 + m4][n] = __builtin_amdgcn_mfma_f32_16x16x32_bf16(
              am[m4][kk], b[n][kk], acc[mq * 4 + m4][n], 0, 0, 0);
    }
    __builtin_amdgcn_s_setprio(0);
    SBAR();
  };

  // ---- prologue: tile0 -> buf0, tile1 -> buf1; frags for tile0 (pinned groups)
  STG_A(0, 0, 0, 0); STG_A(0, 1, 0, 0); STG_A(0, 0, 1, 0); STG_A(0, 1, 1, 0);
  STG_B(0, 0, 0, 0); STG_B(0, 0, 1, 0); STG_B(0, 1, 0, 0); STG_B(0, 1, 1, 0);
  STG_A(1, 0, 0, 1); STG_A(1, 1, 0, 1); STG_A(1, 0, 1, 1); STG_A(1, 1, 1, 1);
  STG_B(1, 0, 0, 1); STG_B(1, 0, 1, 1); STG_B(1, 1, 0, 1); STG_B(1, 1, 1, 1);
  VMCNT(8);
  BARR();
  RD_Ax(0, 0, aE, 0, 3); SBAR();   // group 1: 8 reads (aE)
  RD_B2(0, 0); SBAR();             // group 2: 8 reads (b0,b1)
  RD_B2(0, 1); SBAR();             // group 3: 8 reads (b2,b3)

  // ---- 8 iterations x 2 tiles x 2 phases; counted-lgkm sub-clusters.
  for (int it = 0; it < 8; ++it) {
    int tn = (2 * it + 2) & 15, un = (2 * it + 3) & 15;
#pragma unroll
    for (int half = 0; half < 2; ++half) {
      int bf = half, nb = half ^ 1;
      int kt = half ? un : tn;
      // ph1: aE + b0,b1 ready at lgkm(8) (b2,b3 still in flight)
      LGKM(8);
      MFMA_N(aE, 0, 0, 1);
      LGKM(0);
      MFMA_N(aE, 0, 2, 3);
      RD_Ax(bf, 1, aO, 0, 3); SBAR();  // 8 reads, order m4 0..3
      STG_A(bf, 0, 0, kt); STG_A(bf, 1, 0, kt);
      STG_B(bf, 0, 0, kt); STG_B(bf, 0, 1, kt);
      BARR();
      // ph2: aO[0..1] ready at lgkm(4)
      LGKM(4);
      MFMA_M(aO, 1, 0, 1);
      LGKM(0);
      MFMA_M(aO, 1, 2, 3);
      STG_A(bf, 0, 1, kt); STG_A(bf, 1, 1, kt);
      STG_B(bf, 1, 0, kt); STG_B(bf, 1, 1, kt);
      VMCNT(8);  // nb's tile fully landed before its frag reads below
      RD_Ax(nb, 0, aE, 0, 3); SBAR();
      RD_B2(nb, 0); SBAR();
      RD_B2(nb, 1); SBAR();
      BARR();
    }
  }
  LGKM(0);   // drain tail frag reads
  VMCNT(0);  // drain wrapped dummy stages before epilogue

  // ---- epilogue
  int gcol0 = ct * 256 + wc * 64;
#pragma unroll
  for (int m = 0; m < 8; ++m) {
    int rbase = row0 + wr * 128 + m * 16 + ((lane >> 4) << 2);
#pragma unroll
    for (int j = 0; j < 4; ++j) {
      int grow = rbase + j;
#pragma unroll
      for (int n = 0; n < 4; ++n) {
        int gc = gcol0 + n * 16 + l15;
        float v = acc[m][n][j] + bia[gc];
        if (UP) {
          v = v / (1.f + __expf(-v));  // silu
          OutB[(size_t)grow * DH + gc] = f2bf(v);
        } else if (e < NE) {
          OutB[(size_t)grow * DM + gc] = f2bf(v * rw[grow]);
        } else {
          OutF[(size_t)(grow - po8) * DM + gc] = v;  // shared -> out fp32
        }
      }
    }
  }
}

// ---------------- final combine: out[t] += YE[s0] + YE[s1] ----------------
__global__ __launch_bounds__(256) void k_combine(float* __restrict__ out,
                                                 const unsigned short* __restrict__ YE,
                                                 const int* __restrict__ slot_of) {
  int t = blockIdx.x;
  int s0 = slot_of[t * 2 + 0], s1 = slot_of[t * 2 + 1];
  int c = threadIdx.x * 4;
  float* op = out + (size_t)t * DM + c;
  float4 o = *(float4*)op;
  ushort4 a = *(const ushort4*)(YE + (size_t)s0 * DM + c);
  ushort4 b = *(const ushort4*)(YE + (size_t)s1 * DM + c);
  o.x += bf2f(a.x) + bf2f(b.x);
  o.y += bf2f(a.y) + bf2f(b.y);
  o.z += bf2f(a.z) + bf2f(b.z);
  o.w += bf2f(a.w) + bf2f(b.w);
  *(float4*)op = o;
}

extern "C" void kernel_launch(void* const* d_in, const int* in_sizes, int n_in,
                              void* d_out, int out_size, void* d_ws, size_t ws_size,
                              hipStream_t stream) {
  const float* x        = (const float*)d_in[0];
  const float* gate_w   = (const float*)d_in[1];
  const float* up_w     = (const float*)d_in[2];
  const float* up_b     = (const float*)d_in[3];
  const float* down_w   = (const float*)d_in[4];
  const float* down_b   = (const float*)d_in[5];
  const float* sh_up_w  = (const float*)d_in[6];
  const float* sh_up_b  = (const float*)d_in[7];
  const float* sh_dn_w  = (const float*)d_in[8];
  const float* sh_dn_b  = (const float*)d_in[9];
  float* out = (float*)d_out;

  char* ws = (char*)d_ws;
  const size_t MB = 1024 * 1024;
  unsigned short* xb   = (unsigned short*)(ws + 0);          // 8 MB
  unsigned short* upT  = (unsigned short*)(ws + 8 * MB);     // 16 MB
  unsigned short* dnT  = (unsigned short*)(ws + 24 * MB);    // 16 MB
  unsigned short* shuT = (unsigned short*)(ws + 40 * MB);    // 2 MB
  unsigned short* shdT = (unsigned short*)(ws + 42 * MB);    // 2 MB
  unsigned short* H    = (unsigned short*)(ws + 44 * MB);    // 28 MB (14336*1024*2)
  char* tail = ws + 44 * MB + (size_t)MAXSLOT_ALL * DH * 2;
  int*   tok_e   = (int*)tail;                tail += NASSIGN * 4;
  float* tok_w   = (float*)tail;              tail += NASSIGN * 4;
  int*   slot_of = (int*)tail;                tail += NASSIGN * 4;
  int*   rows    = (int*)tail;                tail += MAXSLOT_ALL * 4;
  float* rw      = (float*)tail;              tail += MAXSLOT_ALL * 4;
  int*   po      = (int*)tail;                tail += 64;
  unsigned short* YE = (unsigned short*)(ws + 0);  // alias xb+upT (20 MB < 24 MB)

  // 1) one dispatch: weight transposes + fused x-convert/route; then slot sort
  k_prep<<<4608 + NTOK / 4, 256, 0, stream>>>(up_w, down_w, sh_up_w, sh_dn_w,
                                              upT, dnT, shuT, shdT,
                                              x, gate_w, xb, tok_e, tok_w);
  k_slots<<<1, 1024, 0, stream>>>(tok_e, tok_w, rows, rw, slot_of, po);

  // 2) grouped GEMMs (experts 0..7 + shared as 8), 256x256, counted-lgkm phases
  k_gemm<true><<<GRID_G, 512, 0, stream>>>(
      xb, upT, shuT, up_b, sh_up_b, rows, rw, po, H, nullptr);
  k_gemm<false><<<GRID_G, 512, 0, stream>>>(
      H, dnT, shdT, down_b, sh_dn_b, rows, rw, po, YE, out);

  // 3) combine
  k_combine<<<NTOK, 256, 0, stream>>>(out, YE, slot_of);
}